// Round 6
// baseline (6932.160 us; speedup 1.0000x reference)
//
#include <hip/hip_runtime.h>
#include <hip/hip_bf16.h>
#include <math.h>

typedef __hip_bfloat16 bf16;

#define NBATCH 4
#define NPTS   8192
#define TOTPTS 32768
#define DIM    128
#define DOUT   256
#define KNN    16
#define CHUNK  1024
#define NCHUNK 8   // NPTS / CHUNK

__device__ __forceinline__ float b2f(bf16 x) { return __bfloat162float(x); }
__device__ __forceinline__ bf16 f2b(float x) { return __float2bfloat16(x); }

__device__ __forceinline__ float rsum32(float v) {
#pragma unroll
  for (int o = 16; o; o >>= 1) v += __shfl_down(v, o, 32);
  return v;
}

// ---------------------------------------------------------------------------
// Pack xyz -> (x, y, z, |p|^2) float4, so the KNN hot loop does one uniform
// 16B load per candidate (scalarizes to s_load_dwordx4, prefetched ahead).
// ---------------------------------------------------------------------------
__global__ __launch_bounds__(256) void pack_kernel(const float* __restrict__ xyz,
                                                   float4* __restrict__ xyzw) {
  const int p = blockIdx.x * 256 + threadIdx.x;
  const float x = xyz[3 * p], y = xyz[3 * p + 1], z = xyz[3 * p + 2];
  xyzw[p] = make_float4(x, y, z, x * x + y * y + z * z);
}

// ---------------------------------------------------------------------------
// KNN phase 1: one thread per (query, 1024-candidate chunk). 2048 blocks of
// 128 threads, no LDS, __launch_bounds__(128,8) -> 32 waves/CU. Candidate
// reads are wave-uniform -> scalar loads (no ds_read on the critical path).
// Ladder uses strict < only: candidates scanned in ascending index, so stored
// entries always have smaller idx — reproduces jax.lax.top_k stable ordering.
// ---------------------------------------------------------------------------
__global__ __launch_bounds__(128, 8) void knn_part_kernel(
    const float4* __restrict__ xyzw,
    float* __restrict__ pd, unsigned short* __restrict__ pi) {
  const int g = blockIdx.x >> 3;        // query group (256 groups of 128)
  const int s = blockIdx.x & 7;         // chunk id
  const int q = g * 128 + threadIdx.x;  // global query id; batch uniform/block
  const int b = q >> 13;
  const float4 me = xyzw[q];
  const float qx = me.x, qy = me.y, qz = me.z, qs = me.w;
  const float4* cb = xyzw + (size_t)b * NPTS + s * CHUNK;  // uniform base
  const int c0 = s * CHUNK;
  float bd[KNN];
  int   bi[KNN];
#pragma unroll
  for (int i = 0; i < KNN; i++) { bd[i] = INFINITY; bi[i] = 0x7fff; }
  for (int j = 0; j < CHUNK; j++) {
    const float4 t = cb[j];             // uniform index -> scalar load
    const float d2 = qs + t.w - 2.f * (qx * t.x + qy * t.y + qz * t.z);
    if (d2 < bd[KNN - 1]) {
      float cd = d2; int ci = c0 + j;
#pragma unroll
      for (int i = 0; i < KNN; i++) {
        const bool sw = cd < bd[i];
        const float td = bd[i]; const int ti = bi[i];
        if (sw) { bd[i] = cd; bi[i] = ci; cd = td; ci = ti; }
      }
    }
  }
  const size_t base = ((size_t)q * NCHUNK + s) * KNN;
#pragma unroll
  for (int i = 0; i < KNN; i++) {
    pd[base + i] = bd[i];
    pi[base + i] = (unsigned short)bi[i];
  }
}

// ---------------------------------------------------------------------------
// KNN phase 2: per query, merge 8 sorted 16-lists. Sorted sublists allow
// early break (first non-inserting element ends its sublist). Chunks merged
// in ascending index-range order -> strict < keeps stable top_k semantics.
// ---------------------------------------------------------------------------
__global__ __launch_bounds__(256) void knn_merge_kernel(
    const float* __restrict__ pd, const unsigned short* __restrict__ pi,
    unsigned short* __restrict__ knn_out) {
  const int q = blockIdx.x * 256 + threadIdx.x;
  float bd[KNN];
  int   bi[KNN];
#pragma unroll
  for (int i = 0; i < KNN; i++) { bd[i] = INFINITY; bi[i] = 0x7fff; }
  const size_t base = (size_t)q * NCHUNK * KNN;
  for (int s = 0; s < NCHUNK; s++) {
    const size_t sb = base + (size_t)s * KNN;
    for (int k = 0; k < KNN; k++) {
      float cd = pd[sb + k];
      if (!(cd < bd[KNN - 1])) break;   // rest of sorted sublist can't insert
      int ci = (int)pi[sb + k];
#pragma unroll
      for (int i = 0; i < KNN; i++) {
        const bool sw = cd < bd[i];
        const float td = bd[i]; const int ti = bi[i];
        if (sw) { bd[i] = cd; bi[i] = ci; cd = td; ci = ti; }
      }
    }
  }
#pragma unroll
  for (int i = 0; i < KNN; i++)
    knn_out[(size_t)q * KNN + i] = (unsigned short)bi[i];
}

// ---------------------------------------------------------------------------
// Projections: per 8 rows compute LN1(features), then Q=f@Wq+bq, Kf=f@Wk+bk,
// Vf=f@Wv+bv (bf16 -> ws) and skip=LN1@Wq+bq (f32 -> d_out out-region).
// ---------------------------------------------------------------------------
__global__ __launch_bounds__(256) void proj_kernel(
    const float* __restrict__ feat,
    const float* __restrict__ Wq, const float* __restrict__ bq,
    const float* __restrict__ Wk, const float* __restrict__ bk,
    const float* __restrict__ Wv, const float* __restrict__ bv,
    const float* __restrict__ g1, const float* __restrict__ b1,
    bf16* __restrict__ Q, bf16* __restrict__ Kf, bf16* __restrict__ Vf,
    float* __restrict__ skip) {
  __shared__ float f[8][DIM];
  __shared__ float ln[8][DIM];
  __shared__ float mu8[8], rs8[8];
  const int tid = threadIdx.x;
  const size_t r0 = (size_t)blockIdx.x * 8;
  const float* src = feat + r0 * DIM;
#pragma unroll
  for (int i = 0; i < 4; i++) {
    const int idx = tid + i * 256;
    f[idx >> 7][idx & 127] = src[idx];
  }
  __syncthreads();
  const int r = tid >> 5, j = tid & 31;
  const float a0 = f[r][j], a1 = f[r][j + 32], a2 = f[r][j + 64], a3 = f[r][j + 96];
  float s = rsum32(a0 + a1 + a2 + a3);
  if (!j) mu8[r] = s * (1.f / 128.f);
  __syncthreads();
  const float mu = mu8[r];
  const float d0 = a0 - mu, d1 = a1 - mu, d2 = a2 - mu, d3 = a3 - mu;
  float ss = rsum32(d0 * d0 + d1 * d1 + d2 * d2 + d3 * d3);
  if (!j) rs8[r] = rsqrtf(ss * (1.f / 128.f) + 1e-5f);
  __syncthreads();
  const float rsd = rs8[r];
  ln[r][j]      = d0 * rsd * g1[j]      + b1[j];
  ln[r][j + 32] = d1 * rsd * g1[j + 32] + b1[j + 32];
  ln[r][j + 64] = d2 * rsd * g1[j + 64] + b1[j + 64];
  ln[r][j + 96] = d3 * rsd * g1[j + 96] + b1[j + 96];
  __syncthreads();
  float qa[8] = {}, ka[8] = {}, va[8] = {}, sa[8] = {};
  for (int d = 0; d < DIM; d += 4) {
    const float wq0 = Wq[(d + 0) * DOUT + tid], wq1 = Wq[(d + 1) * DOUT + tid];
    const float wq2 = Wq[(d + 2) * DOUT + tid], wq3 = Wq[(d + 3) * DOUT + tid];
    const float wk0 = Wk[(d + 0) * DOUT + tid], wk1 = Wk[(d + 1) * DOUT + tid];
    const float wk2 = Wk[(d + 2) * DOUT + tid], wk3 = Wk[(d + 3) * DOUT + tid];
    const float wv0 = Wv[(d + 0) * DOUT + tid], wv1 = Wv[(d + 1) * DOUT + tid];
    const float wv2 = Wv[(d + 2) * DOUT + tid], wv3 = Wv[(d + 3) * DOUT + tid];
#pragma unroll
    for (int rr = 0; rr < 8; rr++) {
      const float4 fv = *(const float4*)&f[rr][d];
      const float4 lv = *(const float4*)&ln[rr][d];
      qa[rr] += fv.x * wq0 + fv.y * wq1 + fv.z * wq2 + fv.w * wq3;
      ka[rr] += fv.x * wk0 + fv.y * wk1 + fv.z * wk2 + fv.w * wk3;
      va[rr] += fv.x * wv0 + fv.y * wv1 + fv.z * wv2 + fv.w * wv3;
      sa[rr] += lv.x * wq0 + lv.y * wq1 + lv.z * wq2 + lv.w * wq3;
    }
  }
  const float bqv = bq[tid], bkv = bk[tid], bvv = bv[tid];
#pragma unroll
  for (int rr = 0; rr < 8; rr++) {
    const size_t o = (r0 + rr) * DOUT + tid;
    Q[o]    = f2b(qa[rr] + bqv);
    Kf[o]   = f2b(ka[rr] + bkv);
    Vf[o]   = f2b(va[rr] + bvv);
    skip[o] = sa[rr] + bqv;
  }
}

// ---------------------------------------------------------------------------
// Attention: one block per point. pos-MLP, gather projected K/V rows to LDS
// (padded stride 257 to break bank conflicts), logits, softmax, weighted sum.
// Q and OA alias the same buffer: block p reads row p (to LDS) before writing
// row p at the end — race-free. Writes attn weights (f32) into d_out.
// ---------------------------------------------------------------------------
__global__ __launch_bounds__(256) void attn_kernel(
    const float* __restrict__ xyz, const unsigned short* __restrict__ knn_in,
    bf16* __restrict__ QOA, const bf16* __restrict__ Kf, const bf16* __restrict__ Vf,
    const float* __restrict__ Wp1, const float* __restrict__ bp1,
    const float* __restrict__ Wp2, const float* __restrict__ bp2,
    float* __restrict__ AOUT) {
  __shared__ int   nidx[16];
  __shared__ float rel[16][4];
  __shared__ float h1s[16][64];
  __shared__ float pos[16][65];
  __shared__ float qv[256];
  __shared__ float kfs[16][257];
  __shared__ float vfs[16][257];
  __shared__ float lg[4][16];
  __shared__ float aw[4][16];
  const int tid = threadIdx.x;
  const int p = blockIdx.x;
  const int b = p >> 13, n = p & (NPTS - 1);
  if (tid < 16) nidx[tid] = knn_in[(size_t)p * KNN + tid];
  qv[tid] = b2f(QOA[(size_t)p * DOUT + tid]);
  __syncthreads();
  if (tid < 48) {
    const int k = tid / 3, c = tid - 3 * k;
    const float* xb = xyz + (size_t)b * NPTS * 3;
    rel[k][c] = xb[3 * nidx[k] + c] - xb[3 * n + c];
  }
  __syncthreads();
#pragma unroll
  for (int i = 0; i < 4; i++) {     // h1 = relu(rel @ Wp1 + bp1)
    const int it = tid + i * 256;
    const int k = it >> 6, d = it & 63;
    const float h = bp1[d] + rel[k][0] * Wp1[d] +
                    rel[k][1] * Wp1[64 + d] + rel[k][2] * Wp1[128 + d];
    h1s[k][d] = fmaxf(h, 0.f);
  }
#pragma unroll
  for (int k = 0; k < 16; k++) {    // gather projected K/V rows (coalesced)
    const size_t row = ((size_t)b * NPTS + nidx[k]) * DOUT;
    kfs[k][tid] = b2f(Kf[row + tid]);
    vfs[k][tid] = b2f(Vf[row + tid]);
  }
  __syncthreads();
#pragma unroll
  for (int i = 0; i < 4; i++) {     // pos = h1 @ Wp2 + bp2
    const int it = tid + i * 256;
    const int k = it >> 6, d = it & 63;
    float acc = bp2[d];
    for (int j2 = 0; j2 < 64; j2++) acc += h1s[k][j2] * Wp2[j2 * 64 + d];
    pos[k][d] = acc;
  }
  __syncthreads();
  if (tid < 64) {                   // logits
    const int k = tid >> 2, h = tid & 3;
    float acc = 0.f;
    for (int d = 0; d < 64; d++)
      acc += qv[h * 64 + d] * (kfs[k][h * 64 + d] + pos[k][d]);
    lg[h][k] = acc * 0.125f;
  }
  __syncthreads();
  if (tid < 4) {                    // softmax over K per head
    const int h = tid;
    float m = -INFINITY;
#pragma unroll
    for (int k = 0; k < 16; k++) m = fmaxf(m, lg[h][k]);
    float e[16], sum = 0.f;
#pragma unroll
    for (int k = 0; k < 16; k++) { e[k] = expf(lg[h][k] - m); sum += e[k]; }
    const float inv = 1.f / sum;
#pragma unroll
    for (int k = 0; k < 16; k++) {
      const float a = e[k] * inv;
      aw[h][k] = a;
      AOUT[(((size_t)b * 4 + h) * NPTS + n) * KNN + k] = a;
    }
  }
  __syncthreads();
  {                                 // out = sum_k attn * (v + pos) -> overwrite Q row
    const int h = tid >> 6, d = tid & 63;
    float acc = 0.f;
#pragma unroll
    for (int k = 0; k < 16; k++) acc += aw[h][k] * (vfs[k][h * 64 + d] + pos[k][d]);
    QOA[(size_t)p * DOUT + tid] = f2b(acc);
  }
}

// ---------------------------------------------------------------------------
// FFN + LN2 + residual: per 8 rows: fc1=relu(x@Wf1+bf1), fc2=fc1@Wf2+bf2,
// out = LN2(fc2)*g2+b2 + skip. skip lives in d_out (f32; read, then
// overwritten by the same thread/element with the final f32 value).
// ---------------------------------------------------------------------------
__global__ __launch_bounds__(256) void ffn_kernel(
    const bf16* __restrict__ OA,
    const float* __restrict__ Wf1, const float* __restrict__ bf1,
    const float* __restrict__ Wf2, const float* __restrict__ bf2,
    const float* __restrict__ g2, const float* __restrict__ b2p,
    float* __restrict__ out) {
  __shared__ float x[8][DOUT];
  __shared__ float y[8][DOUT];
  __shared__ float mu8[8], rs8[8];
  const int tid = threadIdx.x;
  const size_t r0 = (size_t)blockIdx.x * 8;
  const bf16* src = OA + r0 * DOUT;
#pragma unroll
  for (int i = 0; i < 8; i++) x[i][tid] = b2f(src[i * DOUT + tid]);
  __syncthreads();
  float acc[8] = {};
  for (int d = 0; d < DOUT; d += 4) {
    const float w0 = Wf1[(d + 0) * DOUT + tid];
    const float w1 = Wf1[(d + 1) * DOUT + tid];
    const float w2 = Wf1[(d + 2) * DOUT + tid];
    const float w3 = Wf1[(d + 3) * DOUT + tid];
#pragma unroll
    for (int rr = 0; rr < 8; rr++) {
      const float4 v = *(const float4*)&x[rr][d];
      acc[rr] += v.x * w0 + v.y * w1 + v.z * w2 + v.w * w3;
    }
  }
  const float b1v = bf1[tid];
#pragma unroll
  for (int rr = 0; rr < 8; rr++) y[rr][tid] = fmaxf(acc[rr] + b1v, 0.f);
  __syncthreads();
  float acc2[8] = {};
  for (int d = 0; d < DOUT; d += 4) {
    const float w0 = Wf2[(d + 0) * DOUT + tid];
    const float w1 = Wf2[(d + 1) * DOUT + tid];
    const float w2 = Wf2[(d + 2) * DOUT + tid];
    const float w3 = Wf2[(d + 3) * DOUT + tid];
#pragma unroll
    for (int rr = 0; rr < 8; rr++) {
      const float4 v = *(const float4*)&y[rr][d];
      acc2[rr] += v.x * w0 + v.y * w1 + v.z * w2 + v.w * w3;
    }
  }
  const float b2v = bf2[tid];
#pragma unroll
  for (int rr = 0; rr < 8; rr++) x[rr][tid] = acc2[rr] + b2v;   // fc2 -> x
  __syncthreads();
  const int r = tid >> 5, j = tid & 31;
  float s = 0.f;
#pragma unroll
  for (int k2 = 0; k2 < 8; k2++) s += x[r][j + 32 * k2];
  s = rsum32(s);
  if (!j) mu8[r] = s * (1.f / 256.f);
  __syncthreads();
  const float mu = mu8[r];
  float ss = 0.f;
#pragma unroll
  for (int k2 = 0; k2 < 8; k2++) { const float dd = x[r][j + 32 * k2] - mu; ss += dd * dd; }
  ss = rsum32(ss);
  if (!j) rs8[r] = rsqrtf(ss * (1.f / 256.f) + 1e-5f);
  __syncthreads();
  const float gv = g2[tid], bbv = b2p[tid];
#pragma unroll
  for (int rr = 0; rr < 8; rr++) {
    const size_t o = (r0 + rr) * DOUT + tid;
    const float sk = out[o];        // skip stored here by proj_kernel (f32)
    out[o] = (x[rr][tid] - mu8[rr]) * rs8[rr] * gv + bbv + sk;
  }
}

extern "C" void kernel_launch(void* const* d_in, const int* in_sizes, int n_in,
                              void* d_out, int out_size, void* d_ws, size_t ws_size,
                              hipStream_t stream) {
  const float* xyz  = (const float*)d_in[0];
  const float* feat = (const float*)d_in[1];
  const float* Wq   = (const float*)d_in[2];
  const float* bq   = (const float*)d_in[3];
  const float* Wk   = (const float*)d_in[4];
  const float* bk   = (const float*)d_in[5];
  const float* Wv   = (const float*)d_in[6];
  const float* bv   = (const float*)d_in[7];
  const float* Wp1  = (const float*)d_in[8];
  const float* bp1  = (const float*)d_in[9];
  const float* Wp2  = (const float*)d_in[10];
  const float* bp2  = (const float*)d_in[11];
  const float* Wf1  = (const float*)d_in[12];
  const float* bf1  = (const float*)d_in[13];
  const float* Wf2  = (const float*)d_in[14];
  const float* bf2  = (const float*)d_in[15];
  const float* g1   = (const float*)d_in[16];
  const float* b1   = (const float*)d_in[17];
  const float* g2   = (const float*)d_in[18];
  const float* b2   = (const float*)d_in[19];

  float* out  = (float*)d_out;
  float* aout = out + (size_t)TOTPTS * DOUT;  // attn-weights output region (f32)

  // workspace layout (49 MB peak):
  //   [0, 1 MB)    final knn indices, uint16 (persists through attn)
  //   [1, 17 MB)   phase: knn partial dists f32  -> later QOA bf16 (proj/attn)
  //   [17, ~25.4)  phase: knn partial idx u16    -> later part of Kf
  //   [26, 26.5)   phase: packed xyzw float4     -> later part of Kf
  //   [17, 33 MB)  Kf bf16 (proj onward)
  //   [33, 49 MB)  Vf bf16
  // knn scratch is dead before proj_kernel writes QOA/Kf (stream-ordered).
  unsigned short* knn  = (unsigned short*)d_ws;
  float*          pd   = (float*)((char*)d_ws + (size_t)(1 << 20));
  unsigned short* pi   = (unsigned short*)((char*)d_ws + (size_t)(17 << 20));
  float4*         xyzw = (float4*)((char*)d_ws + (size_t)(26 << 20));
  bf16* QOA = (bf16*)((char*)d_ws + (size_t)(1 << 20));
  bf16* Kf  = QOA + (size_t)TOTPTS * DOUT;
  bf16* Vf  = Kf  + (size_t)TOTPTS * DOUT;

  pack_kernel<<<TOTPTS / 256, 256, 0, stream>>>(xyz, xyzw);
  knn_part_kernel<<<(TOTPTS / 128) * NCHUNK, 128, 0, stream>>>(xyzw, pd, pi);
  knn_merge_kernel<<<TOTPTS / 256, 256, 0, stream>>>(pd, pi, knn);
  proj_kernel<<<TOTPTS / 8, 256, 0, stream>>>(feat, Wq, bq, Wk, bk, Wv, bv, g1, b1,
                                              QOA, Kf, Vf, /*skip->*/out);
  attn_kernel<<<TOTPTS, 256, 0, stream>>>(xyz, knn, QOA, Kf, Vf, Wp1, bp1, Wp2, bp2,
                                          aout);
  ffn_kernel<<<TOTPTS / 8, 256, 0, stream>>>(QOA, Wf1, bf1, Wf2, bf2, g2, b2, out);
}

// Round 7
// 4570.026 us; speedup vs baseline: 1.5169x; 1.5169x over previous
//
#include <hip/hip_runtime.h>
#include <hip/hip_bf16.h>
#include <math.h>

typedef __hip_bfloat16 bf16;

#define NBATCH 4
#define NPTS   8192
#define TOTPTS 32768
#define DIM    128
#define DOUT   256
#define KNN    16
#define CHUNK  1024
#define NCHUNK 8   // NPTS / CHUNK

__device__ __forceinline__ float b2f(bf16 x) { return __bfloat162float(x); }
__device__ __forceinline__ bf16 f2b(float x) { return __float2bfloat16(x); }

__device__ __forceinline__ float rsum32(float v) {
#pragma unroll
  for (int o = 16; o; o >>= 1) v += __shfl_down(v, o, 32);
  return v;
}

// ---------------------------------------------------------------------------
// Pack xyz -> (x, y, z, |p|^2) float4 (one 16B load per candidate later).
// ---------------------------------------------------------------------------
__global__ __launch_bounds__(256) void pack_kernel(const float* __restrict__ xyz,
                                                   float4* __restrict__ xyzw) {
  const int p = blockIdx.x * 256 + threadIdx.x;
  const float x = xyz[3 * p], y = xyz[3 * p + 1], z = xyz[3 * p + 2];
  xyzw[p] = make_float4(x, y, z, x * x + y * y + z * z);
}

// ---------------------------------------------------------------------------
// KNN phase 1: one thread per (query, 1024-candidate chunk). 2048 blocks of
// 128 threads (8 blocks/CU, 16 waves/CU), 16 KB LDS tile per block. NO
// launch_bounds register cap — round 6's (128,8) forced bd/bi to spill to
// scratch (WRITE_SIZE 5.9 GB). Inner loop unrolled x4 with a fused min-gate:
// 4 independent d2 chains amortize the LDS-read latency; inserts run in
// ascending candidate order so strict < reproduces stable jax.lax.top_k.
// ---------------------------------------------------------------------------
__global__ __launch_bounds__(128) void knn_part_kernel(
    const float4* __restrict__ xyzw,
    float* __restrict__ pd, unsigned short* __restrict__ pi) {
  __shared__ float4 tile[CHUNK];        // 16 KB
  const int g = blockIdx.x >> 3;        // query group (256 groups of 128)
  const int s = blockIdx.x & 7;         // chunk id
  const int q = g * 128 + threadIdx.x;  // global query id; batch uniform/block
  const int b = q >> 13;
  const float4* cb = xyzw + (size_t)b * NPTS + s * CHUNK;
  for (int i = threadIdx.x; i < CHUNK; i += 128) tile[i] = cb[i];
  const float4 me = xyzw[q];
  const float qx = me.x, qy = me.y, qz = me.z, qs = me.w;
  const int c0 = s * CHUNK;
  __syncthreads();
  float bd[KNN];
  int   bi[KNN];
#pragma unroll
  for (int i = 0; i < KNN; i++) { bd[i] = INFINITY; bi[i] = 0x7fff; }

#define KNN_INSERT(CD, CI)                                        \
  {                                                               \
    float cd = (CD); int ci = (CI);                               \
    _Pragma("unroll")                                             \
    for (int i = 0; i < KNN; i++) {                               \
      const bool sw = cd < bd[i];                                 \
      const float td = bd[i]; const int ti = bi[i];               \
      if (sw) { bd[i] = cd; bi[i] = ci; cd = td; ci = ti; }       \
    }                                                             \
  }

  for (int j = 0; j < CHUNK; j += 4) {
    const float4 t0 = tile[j + 0];
    const float4 t1 = tile[j + 1];
    const float4 t2 = tile[j + 2];
    const float4 t3 = tile[j + 3];
    const float d0 = qs + t0.w - 2.f * (qx * t0.x + qy * t0.y + qz * t0.z);
    const float d1 = qs + t1.w - 2.f * (qx * t1.x + qy * t1.y + qz * t1.z);
    const float d2 = qs + t2.w - 2.f * (qx * t2.x + qy * t2.y + qz * t2.z);
    const float d3 = qs + t3.w - 2.f * (qx * t3.x + qy * t3.y + qz * t3.z);
    const float dmin = fminf(fminf(d0, d1), fminf(d2, d3));
    if (dmin < bd[KNN - 1]) {           // rare gate: enter insert path
      if (d0 < bd[KNN - 1]) KNN_INSERT(d0, c0 + j + 0);
      if (d1 < bd[KNN - 1]) KNN_INSERT(d1, c0 + j + 1);
      if (d2 < bd[KNN - 1]) KNN_INSERT(d2, c0 + j + 2);
      if (d3 < bd[KNN - 1]) KNN_INSERT(d3, c0 + j + 3);
    }
  }
#undef KNN_INSERT
  const size_t base = ((size_t)q * NCHUNK + s) * KNN;
#pragma unroll
  for (int i = 0; i < KNN; i++) {
    pd[base + i] = bd[i];
    pi[base + i] = (unsigned short)bi[i];
  }
}

// ---------------------------------------------------------------------------
// KNN phase 2: per query, merge 8 sorted 16-lists. Sorted sublists allow
// early break. Chunks merged in ascending index-range order -> strict <
// keeps stable top_k semantics.
// ---------------------------------------------------------------------------
__global__ __launch_bounds__(256) void knn_merge_kernel(
    const float* __restrict__ pd, const unsigned short* __restrict__ pi,
    unsigned short* __restrict__ knn_out) {
  const int q = blockIdx.x * 256 + threadIdx.x;
  float bd[KNN];
  int   bi[KNN];
#pragma unroll
  for (int i = 0; i < KNN; i++) { bd[i] = INFINITY; bi[i] = 0x7fff; }
  const size_t base = (size_t)q * NCHUNK * KNN;
  for (int s = 0; s < NCHUNK; s++) {
    const size_t sb = base + (size_t)s * KNN;
    for (int k = 0; k < KNN; k++) {
      float cd = pd[sb + k];
      if (!(cd < bd[KNN - 1])) break;   // rest of sorted sublist can't insert
      int ci = (int)pi[sb + k];
#pragma unroll
      for (int i = 0; i < KNN; i++) {
        const bool sw = cd < bd[i];
        const float td = bd[i]; const int ti = bi[i];
        if (sw) { bd[i] = cd; bi[i] = ci; cd = td; ci = ti; }
      }
    }
  }
#pragma unroll
  for (int i = 0; i < KNN; i++)
    knn_out[(size_t)q * KNN + i] = (unsigned short)bi[i];
}

// ---------------------------------------------------------------------------
// Projections: per 8 rows compute LN1(features), then Q=f@Wq+bq, Kf=f@Wk+bk,
// Vf=f@Wv+bv (bf16 -> ws) and skip=LN1@Wq+bq (f32 -> d_out out-region).
// ---------------------------------------------------------------------------
__global__ __launch_bounds__(256) void proj_kernel(
    const float* __restrict__ feat,
    const float* __restrict__ Wq, const float* __restrict__ bq,
    const float* __restrict__ Wk, const float* __restrict__ bk,
    const float* __restrict__ Wv, const float* __restrict__ bv,
    const float* __restrict__ g1, const float* __restrict__ b1,
    bf16* __restrict__ Q, bf16* __restrict__ Kf, bf16* __restrict__ Vf,
    float* __restrict__ skip) {
  __shared__ float f[8][DIM];
  __shared__ float ln[8][DIM];
  __shared__ float mu8[8], rs8[8];
  const int tid = threadIdx.x;
  const size_t r0 = (size_t)blockIdx.x * 8;
  const float* src = feat + r0 * DIM;
#pragma unroll
  for (int i = 0; i < 4; i++) {
    const int idx = tid + i * 256;
    f[idx >> 7][idx & 127] = src[idx];
  }
  __syncthreads();
  const int r = tid >> 5, j = tid & 31;
  const float a0 = f[r][j], a1 = f[r][j + 32], a2 = f[r][j + 64], a3 = f[r][j + 96];
  float s = rsum32(a0 + a1 + a2 + a3);
  if (!j) mu8[r] = s * (1.f / 128.f);
  __syncthreads();
  const float mu = mu8[r];
  const float d0 = a0 - mu, d1 = a1 - mu, d2 = a2 - mu, d3 = a3 - mu;
  float ss = rsum32(d0 * d0 + d1 * d1 + d2 * d2 + d3 * d3);
  if (!j) rs8[r] = rsqrtf(ss * (1.f / 128.f) + 1e-5f);
  __syncthreads();
  const float rsd = rs8[r];
  ln[r][j]      = d0 * rsd * g1[j]      + b1[j];
  ln[r][j + 32] = d1 * rsd * g1[j + 32] + b1[j + 32];
  ln[r][j + 64] = d2 * rsd * g1[j + 64] + b1[j + 64];
  ln[r][j + 96] = d3 * rsd * g1[j + 96] + b1[j + 96];
  __syncthreads();
  float qa[8] = {}, ka[8] = {}, va[8] = {}, sa[8] = {};
  for (int d = 0; d < DIM; d += 4) {
    const float wq0 = Wq[(d + 0) * DOUT + tid], wq1 = Wq[(d + 1) * DOUT + tid];
    const float wq2 = Wq[(d + 2) * DOUT + tid], wq3 = Wq[(d + 3) * DOUT + tid];
    const float wk0 = Wk[(d + 0) * DOUT + tid], wk1 = Wk[(d + 1) * DOUT + tid];
    const float wk2 = Wk[(d + 2) * DOUT + tid], wk3 = Wk[(d + 3) * DOUT + tid];
    const float wv0 = Wv[(d + 0) * DOUT + tid], wv1 = Wv[(d + 1) * DOUT + tid];
    const float wv2 = Wv[(d + 2) * DOUT + tid], wv3 = Wv[(d + 3) * DOUT + tid];
#pragma unroll
    for (int rr = 0; rr < 8; rr++) {
      const float4 fv = *(const float4*)&f[rr][d];
      const float4 lv = *(const float4*)&ln[rr][d];
      qa[rr] += fv.x * wq0 + fv.y * wq1 + fv.z * wq2 + fv.w * wq3;
      ka[rr] += fv.x * wk0 + fv.y * wk1 + fv.z * wk2 + fv.w * wk3;
      va[rr] += fv.x * wv0 + fv.y * wv1 + fv.z * wv2 + fv.w * wv3;
      sa[rr] += lv.x * wq0 + lv.y * wq1 + lv.z * wq2 + lv.w * wq3;
    }
  }
  const float bqv = bq[tid], bkv = bk[tid], bvv = bv[tid];
#pragma unroll
  for (int rr = 0; rr < 8; rr++) {
    const size_t o = (r0 + rr) * DOUT + tid;
    Q[o]    = f2b(qa[rr] + bqv);
    Kf[o]   = f2b(ka[rr] + bkv);
    Vf[o]   = f2b(va[rr] + bvv);
    skip[o] = sa[rr] + bqv;
  }
}

// ---------------------------------------------------------------------------
// Attention: one block per point. pos-MLP, gather projected K/V rows to LDS
// (padded stride 257 to break bank conflicts), logits, softmax, weighted sum.
// Q and OA alias the same buffer: block p reads row p (to LDS) before writing
// row p at the end — race-free. Writes attn weights (f32) into d_out.
// ---------------------------------------------------------------------------
__global__ __launch_bounds__(256) void attn_kernel(
    const float* __restrict__ xyz, const unsigned short* __restrict__ knn_in,
    bf16* __restrict__ QOA, const bf16* __restrict__ Kf, const bf16* __restrict__ Vf,
    const float* __restrict__ Wp1, const float* __restrict__ bp1,
    const float* __restrict__ Wp2, const float* __restrict__ bp2,
    float* __restrict__ AOUT) {
  __shared__ int   nidx[16];
  __shared__ float rel[16][4];
  __shared__ float h1s[16][64];
  __shared__ float pos[16][65];
  __shared__ float qv[256];
  __shared__ float kfs[16][257];
  __shared__ float vfs[16][257];
  __shared__ float lg[4][16];
  __shared__ float aw[4][16];
  const int tid = threadIdx.x;
  const int p = blockIdx.x;
  const int b = p >> 13, n = p & (NPTS - 1);
  if (tid < 16) nidx[tid] = knn_in[(size_t)p * KNN + tid];
  qv[tid] = b2f(QOA[(size_t)p * DOUT + tid]);
  __syncthreads();
  if (tid < 48) {
    const int k = tid / 3, c = tid - 3 * k;
    const float* xb = xyz + (size_t)b * NPTS * 3;
    rel[k][c] = xb[3 * nidx[k] + c] - xb[3 * n + c];
  }
  __syncthreads();
#pragma unroll
  for (int i = 0; i < 4; i++) {     // h1 = relu(rel @ Wp1 + bp1)
    const int it = tid + i * 256;
    const int k = it >> 6, d = it & 63;
    const float h = bp1[d] + rel[k][0] * Wp1[d] +
                    rel[k][1] * Wp1[64 + d] + rel[k][2] * Wp1[128 + d];
    h1s[k][d] = fmaxf(h, 0.f);
  }
#pragma unroll
  for (int k = 0; k < 16; k++) {    // gather projected K/V rows (coalesced)
    const size_t row = ((size_t)b * NPTS + nidx[k]) * DOUT;
    kfs[k][tid] = b2f(Kf[row + tid]);
    vfs[k][tid] = b2f(Vf[row + tid]);
  }
  __syncthreads();
#pragma unroll
  for (int i = 0; i < 4; i++) {     // pos = h1 @ Wp2 + bp2
    const int it = tid + i * 256;
    const int k = it >> 6, d = it & 63;
    float acc = bp2[d];
    for (int j2 = 0; j2 < 64; j2++) acc += h1s[k][j2] * Wp2[j2 * 64 + d];
    pos[k][d] = acc;
  }
  __syncthreads();
  if (tid < 64) {                   // logits
    const int k = tid >> 2, h = tid & 3;
    float acc = 0.f;
    for (int d = 0; d < 64; d++)
      acc += qv[h * 64 + d] * (kfs[k][h * 64 + d] + pos[k][d]);
    lg[h][k] = acc * 0.125f;
  }
  __syncthreads();
  if (tid < 4) {                    // softmax over K per head
    const int h = tid;
    float m = -INFINITY;
#pragma unroll
    for (int k = 0; k < 16; k++) m = fmaxf(m, lg[h][k]);
    float e[16], sum = 0.f;
#pragma unroll
    for (int k = 0; k < 16; k++) { e[k] = expf(lg[h][k] - m); sum += e[k]; }
    const float inv = 1.f / sum;
#pragma unroll
    for (int k = 0; k < 16; k++) {
      const float a = e[k] * inv;
      aw[h][k] = a;
      AOUT[(((size_t)b * 4 + h) * NPTS + n) * KNN + k] = a;
    }
  }
  __syncthreads();
  {                                 // out = sum_k attn * (v + pos) -> overwrite Q row
    const int h = tid >> 6, d = tid & 63;
    float acc = 0.f;
#pragma unroll
    for (int k = 0; k < 16; k++) acc += aw[h][k] * (vfs[k][h * 64 + d] + pos[k][d]);
    QOA[(size_t)p * DOUT + tid] = f2b(acc);
  }
}

// ---------------------------------------------------------------------------
// FFN + LN2 + residual: per 8 rows: fc1=relu(x@Wf1+bf1), fc2=fc1@Wf2+bf2,
// out = LN2(fc2)*g2+b2 + skip. skip lives in d_out (f32; read, then
// overwritten by the same thread/element with the final f32 value).
// ---------------------------------------------------------------------------
__global__ __launch_bounds__(256) void ffn_kernel(
    const bf16* __restrict__ OA,
    const float* __restrict__ Wf1, const float* __restrict__ bf1,
    const float* __restrict__ Wf2, const float* __restrict__ bf2,
    const float* __restrict__ g2, const float* __restrict__ b2p,
    float* __restrict__ out) {
  __shared__ float x[8][DOUT];
  __shared__ float y[8][DOUT];
  __shared__ float mu8[8], rs8[8];
  const int tid = threadIdx.x;
  const size_t r0 = (size_t)blockIdx.x * 8;
  const bf16* src = OA + r0 * DOUT;
#pragma unroll
  for (int i = 0; i < 8; i++) x[i][tid] = b2f(src[i * DOUT + tid]);
  __syncthreads();
  float acc[8] = {};
  for (int d = 0; d < DOUT; d += 4) {
    const float w0 = Wf1[(d + 0) * DOUT + tid];
    const float w1 = Wf1[(d + 1) * DOUT + tid];
    const float w2 = Wf1[(d + 2) * DOUT + tid];
    const float w3 = Wf1[(d + 3) * DOUT + tid];
#pragma unroll
    for (int rr = 0; rr < 8; rr++) {
      const float4 v = *(const float4*)&x[rr][d];
      acc[rr] += v.x * w0 + v.y * w1 + v.z * w2 + v.w * w3;
    }
  }
  const float b1v = bf1[tid];
#pragma unroll
  for (int rr = 0; rr < 8; rr++) y[rr][tid] = fmaxf(acc[rr] + b1v, 0.f);
  __syncthreads();
  float acc2[8] = {};
  for (int d = 0; d < DOUT; d += 4) {
    const float w0 = Wf2[(d + 0) * DOUT + tid];
    const float w1 = Wf2[(d + 1) * DOUT + tid];
    const float w2 = Wf2[(d + 2) * DOUT + tid];
    const float w3 = Wf2[(d + 3) * DOUT + tid];
#pragma unroll
    for (int rr = 0; rr < 8; rr++) {
      const float4 v = *(const float4*)&y[rr][d];
      acc2[rr] += v.x * w0 + v.y * w1 + v.z * w2 + v.w * w3;
    }
  }
  const float b2v = bf2[tid];
#pragma unroll
  for (int rr = 0; rr < 8; rr++) x[rr][tid] = acc2[rr] + b2v;   // fc2 -> x
  __syncthreads();
  const int r = tid >> 5, j = tid & 31;
  float s = 0.f;
#pragma unroll
  for (int k2 = 0; k2 < 8; k2++) s += x[r][j + 32 * k2];
  s = rsum32(s);
  if (!j) mu8[r] = s * (1.f / 256.f);
  __syncthreads();
  const float mu = mu8[r];
  float ss = 0.f;
#pragma unroll
  for (int k2 = 0; k2 < 8; k2++) { const float dd = x[r][j + 32 * k2] - mu; ss += dd * dd; }
  ss = rsum32(ss);
  if (!j) rs8[r] = rsqrtf(ss * (1.f / 256.f) + 1e-5f);
  __syncthreads();
  const float gv = g2[tid], bbv = b2p[tid];
#pragma unroll
  for (int rr = 0; rr < 8; rr++) {
    const size_t o = (r0 + rr) * DOUT + tid;
    const float sk = out[o];        // skip stored here by proj_kernel (f32)
    out[o] = (x[rr][tid] - mu8[rr]) * rs8[rr] * gv + bbv + sk;
  }
}

extern "C" void kernel_launch(void* const* d_in, const int* in_sizes, int n_in,
                              void* d_out, int out_size, void* d_ws, size_t ws_size,
                              hipStream_t stream) {
  const float* xyz  = (const float*)d_in[0];
  const float* feat = (const float*)d_in[1];
  const float* Wq   = (const float*)d_in[2];
  const float* bq   = (const float*)d_in[3];
  const float* Wk   = (const float*)d_in[4];
  const float* bk   = (const float*)d_in[5];
  const float* Wv   = (const float*)d_in[6];
  const float* bv   = (const float*)d_in[7];
  const float* Wp1  = (const float*)d_in[8];
  const float* bp1  = (const float*)d_in[9];
  const float* Wp2  = (const float*)d_in[10];
  const float* bp2  = (const float*)d_in[11];
  const float* Wf1  = (const float*)d_in[12];
  const float* bf1  = (const float*)d_in[13];
  const float* Wf2  = (const float*)d_in[14];
  const float* bf2  = (const float*)d_in[15];
  const float* g1   = (const float*)d_in[16];
  const float* b1   = (const float*)d_in[17];
  const float* g2   = (const float*)d_in[18];
  const float* b2   = (const float*)d_in[19];

  float* out  = (float*)d_out;
  float* aout = out + (size_t)TOTPTS * DOUT;  // attn-weights output region (f32)

  // workspace layout (49 MB peak):
  //   [0, 1 MB)    final knn indices, uint16 (persists through attn)
  //   [1, 17 MB)   phase: knn partial dists f32  -> later QOA bf16 (proj/attn)
  //   [17, ~25.4)  phase: knn partial idx u16    -> later part of Kf
  //   [26, 26.5)   phase: packed xyzw float4     -> later part of Kf
  //   [17, 33 MB)  Kf bf16 (proj onward)
  //   [33, 49 MB)  Vf bf16
  // knn scratch is dead before proj_kernel writes QOA/Kf (stream-ordered).
  unsigned short* knn  = (unsigned short*)d_ws;
  float*          pd   = (float*)((char*)d_ws + (size_t)(1 << 20));
  unsigned short* pi   = (unsigned short*)((char*)d_ws + (size_t)(17 << 20));
  float4*         xyzw = (float4*)((char*)d_ws + (size_t)(26 << 20));
  bf16* QOA = (bf16*)((char*)d_ws + (size_t)(1 << 20));
  bf16* Kf  = QOA + (size_t)TOTPTS * DOUT;
  bf16* Vf  = Kf  + (size_t)TOTPTS * DOUT;

  pack_kernel<<<TOTPTS / 256, 256, 0, stream>>>(xyz, xyzw);
  knn_part_kernel<<<(TOTPTS / 128) * NCHUNK, 128, 0, stream>>>(xyzw, pd, pi);
  knn_merge_kernel<<<TOTPTS / 256, 256, 0, stream>>>(pd, pi, knn);
  proj_kernel<<<TOTPTS / 8, 256, 0, stream>>>(feat, Wq, bq, Wk, bk, Wv, bv, g1, b1,
                                              QOA, Kf, Vf, /*skip->*/out);
  attn_kernel<<<TOTPTS, 256, 0, stream>>>(xyz, knn, QOA, Kf, Vf, Wp1, bp1, Wp2, bp2,
                                          aout);
  ffn_kernel<<<TOTPTS / 8, 256, 0, stream>>>(QOA, Wf1, bf1, Wf2, bf2, g2, b2, out);
}

// Round 8
// 2184.087 us; speedup vs baseline: 3.1739x; 2.0924x over previous
//
#include <hip/hip_runtime.h>
#include <hip/hip_bf16.h>
#include <math.h>

typedef __hip_bfloat16 bf16;

#define NBATCH 4
#define NPTS   8192
#define TOTPTS 32768
#define DIM    128
#define DOUT   256
#define KNN    16

__device__ __forceinline__ float b2f(bf16 x) { return __bfloat162float(x); }
__device__ __forceinline__ bf16 f2b(float x) { return __float2bfloat16(x); }

__device__ __forceinline__ float rsum32(float v) {
#pragma unroll
  for (int o = 16; o; o >>= 1) v += __shfl_down(v, o, 32);
  return v;
}

// ---------------------------------------------------------------------------
// Pack xyz -> (x, y, z, |p|^2) float4 (one coalesced 16B load per candidate).
// ---------------------------------------------------------------------------
__global__ __launch_bounds__(256) void pack_kernel(const float* __restrict__ xyz,
                                                   float4* __restrict__ xyzw) {
  const int p = blockIdx.x * 256 + threadIdx.x;
  const float x = xyz[3 * p], y = xyz[3 * p + 1], z = xyz[3 * p + 2];
  xyzw[p] = make_float4(x, y, z, x * x + y * y + z * z);
}

// ---------------------------------------------------------------------------
// KNN: ONE WAVE PER QUERY, lane = candidate. r5/r7 post-mortem: with
// thread=query mapping, the per-lane insert gate (rate ~8%) fires for SOME
// lane ~100% of wave-iterations -> the wave runs the 80-instr ladder for
// nearly every candidate (430 cyc/cand, body shape irrelevant). Here the
// ballot makes events wave-uniform: ~116 inserts per query total, executed
// with all lanes active on replicated top-16 state (zero divergence).
// Candidates processed in ascending index order (groups ascending, ctz
// extracts ascending lanes); keep-condition bd[i] <= dl preserves
// jax.lax.top_k stable tie order. Exact top-16 -> no merge pass needed.
// ---------------------------------------------------------------------------
__global__ __launch_bounds__(256) void knn_wave_kernel(
    const float4* __restrict__ xyzw, unsigned short* __restrict__ knn_out) {
  const int wid  = threadIdx.x >> 6;
  const int lane = threadIdx.x & 63;
  const int q = blockIdx.x * 4 + wid;     // wave-uniform query id
  const int b = q >> 13;
  const float4 me = xyzw[q];
  const float qx = me.x, qy = me.y, qz = me.z, qs = me.w;
  const float4* cb = xyzw + (size_t)b * NPTS;
  float bd[KNN];
  int   bi[KNN];
#pragma unroll
  for (int i = 0; i < KNN; i++) { bd[i] = INFINITY; bi[i] = 0x7fff; }
  for (int g = 0; g < NPTS; g += 64) {
    const float4 t = cb[g + lane];        // coalesced; 4 waves/block share stream
    const float d2 = qs + t.w - 2.f * (qx * t.x + qy * t.y + qz * t.z);
    unsigned long long mask = __ballot(d2 < bd[KNN - 1]);
    while (mask) {                        // wave-uniform loop
      const int l = __builtin_ctzll(mask);
      mask &= mask - 1;
      const float dl = __int_as_float(
          __builtin_amdgcn_readlane(__float_as_int(d2), l));
      if (dl < bd[KNN - 1]) {             // uniform re-check (bd15 shrinks)
        const int il = g + l;
        float nd[KNN]; int ni[KNN];
#pragma unroll
        for (int i = 0; i < KNN; i++) {   // positional insert, no serial chain
          const bool keep = bd[i] <= dl;  // ties: earlier index stays left
          const bool fromPrev = (i > 0) && (bd[i - 1] > dl);
          nd[i] = keep ? bd[i] : (fromPrev ? bd[i - 1] : dl);
          ni[i] = keep ? bi[i] : (fromPrev ? bi[i - 1] : il);
        }
#pragma unroll
        for (int i = 0; i < KNN; i++) { bd[i] = nd[i]; bi[i] = ni[i]; }
      }
    }
  }
  if (lane == 0) {
#pragma unroll
    for (int i = 0; i < KNN; i++)
      knn_out[(size_t)q * KNN + i] = (unsigned short)bi[i];
  }
}

// ---------------------------------------------------------------------------
// Projections: per 8 rows compute LN1(features), then Q=f@Wq+bq, Kf=f@Wk+bk,
// Vf=f@Wv+bv (bf16 -> ws) and skip=LN1@Wq+bq (f32 -> d_out out-region).
// ---------------------------------------------------------------------------
__global__ __launch_bounds__(256) void proj_kernel(
    const float* __restrict__ feat,
    const float* __restrict__ Wq, const float* __restrict__ bq,
    const float* __restrict__ Wk, const float* __restrict__ bk,
    const float* __restrict__ Wv, const float* __restrict__ bv,
    const float* __restrict__ g1, const float* __restrict__ b1,
    bf16* __restrict__ Q, bf16* __restrict__ Kf, bf16* __restrict__ Vf,
    float* __restrict__ skip) {
  __shared__ float f[8][DIM];
  __shared__ float ln[8][DIM];
  __shared__ float mu8[8], rs8[8];
  const int tid = threadIdx.x;
  const size_t r0 = (size_t)blockIdx.x * 8;
  const float* src = feat + r0 * DIM;
#pragma unroll
  for (int i = 0; i < 4; i++) {
    const int idx = tid + i * 256;
    f[idx >> 7][idx & 127] = src[idx];
  }
  __syncthreads();
  const int r = tid >> 5, j = tid & 31;
  const float a0 = f[r][j], a1 = f[r][j + 32], a2 = f[r][j + 64], a3 = f[r][j + 96];
  float s = rsum32(a0 + a1 + a2 + a3);
  if (!j) mu8[r] = s * (1.f / 128.f);
  __syncthreads();
  const float mu = mu8[r];
  const float d0 = a0 - mu, d1 = a1 - mu, d2 = a2 - mu, d3 = a3 - mu;
  float ss = rsum32(d0 * d0 + d1 * d1 + d2 * d2 + d3 * d3);
  if (!j) rs8[r] = rsqrtf(ss * (1.f / 128.f) + 1e-5f);
  __syncthreads();
  const float rsd = rs8[r];
  ln[r][j]      = d0 * rsd * g1[j]      + b1[j];
  ln[r][j + 32] = d1 * rsd * g1[j + 32] + b1[j + 32];
  ln[r][j + 64] = d2 * rsd * g1[j + 64] + b1[j + 64];
  ln[r][j + 96] = d3 * rsd * g1[j + 96] + b1[j + 96];
  __syncthreads();
  float qa[8] = {}, ka[8] = {}, va[8] = {}, sa[8] = {};
  for (int d = 0; d < DIM; d += 4) {
    const float wq0 = Wq[(d + 0) * DOUT + tid], wq1 = Wq[(d + 1) * DOUT + tid];
    const float wq2 = Wq[(d + 2) * DOUT + tid], wq3 = Wq[(d + 3) * DOUT + tid];
    const float wk0 = Wk[(d + 0) * DOUT + tid], wk1 = Wk[(d + 1) * DOUT + tid];
    const float wk2 = Wk[(d + 2) * DOUT + tid], wk3 = Wk[(d + 3) * DOUT + tid];
    const float wv0 = Wv[(d + 0) * DOUT + tid], wv1 = Wv[(d + 1) * DOUT + tid];
    const float wv2 = Wv[(d + 2) * DOUT + tid], wv3 = Wv[(d + 3) * DOUT + tid];
#pragma unroll
    for (int rr = 0; rr < 8; rr++) {
      const float4 fv = *(const float4*)&f[rr][d];
      const float4 lv = *(const float4*)&ln[rr][d];
      qa[rr] += fv.x * wq0 + fv.y * wq1 + fv.z * wq2 + fv.w * wq3;
      ka[rr] += fv.x * wk0 + fv.y * wk1 + fv.z * wk2 + fv.w * wk3;
      va[rr] += fv.x * wv0 + fv.y * wv1 + fv.z * wv2 + fv.w * wv3;
      sa[rr] += lv.x * wq0 + lv.y * wq1 + lv.z * wq2 + lv.w * wq3;
    }
  }
  const float bqv = bq[tid], bkv = bk[tid], bvv = bv[tid];
#pragma unroll
  for (int rr = 0; rr < 8; rr++) {
    const size_t o = (r0 + rr) * DOUT + tid;
    Q[o]    = f2b(qa[rr] + bqv);
    Kf[o]   = f2b(ka[rr] + bkv);
    Vf[o]   = f2b(va[rr] + bvv);
    skip[o] = sa[rr] + bqv;
  }
}

// ---------------------------------------------------------------------------
// Attention: one block per point. pos-MLP, gather projected K/V rows to LDS
// (padded stride 257 to break bank conflicts), logits, softmax, weighted sum.
// Q and OA alias the same buffer: block p reads row p (to LDS) before writing
// row p at the end — race-free. Writes attn weights (f32) into d_out.
// ---------------------------------------------------------------------------
__global__ __launch_bounds__(256) void attn_kernel(
    const float* __restrict__ xyz, const unsigned short* __restrict__ knn_in,
    bf16* __restrict__ QOA, const bf16* __restrict__ Kf, const bf16* __restrict__ Vf,
    const float* __restrict__ Wp1, const float* __restrict__ bp1,
    const float* __restrict__ Wp2, const float* __restrict__ bp2,
    float* __restrict__ AOUT) {
  __shared__ int   nidx[16];
  __shared__ float rel[16][4];
  __shared__ float h1s[16][64];
  __shared__ float pos[16][65];
  __shared__ float qv[256];
  __shared__ float kfs[16][257];
  __shared__ float vfs[16][257];
  __shared__ float lg[4][16];
  __shared__ float aw[4][16];
  const int tid = threadIdx.x;
  const int p = blockIdx.x;
  const int b = p >> 13, n = p & (NPTS - 1);
  if (tid < 16) nidx[tid] = knn_in[(size_t)p * KNN + tid];
  qv[tid] = b2f(QOA[(size_t)p * DOUT + tid]);
  __syncthreads();
  if (tid < 48) {
    const int k = tid / 3, c = tid - 3 * k;
    const float* xb = xyz + (size_t)b * NPTS * 3;
    rel[k][c] = xb[3 * nidx[k] + c] - xb[3 * n + c];
  }
  __syncthreads();
#pragma unroll
  for (int i = 0; i < 4; i++) {     // h1 = relu(rel @ Wp1 + bp1)
    const int it = tid + i * 256;
    const int k = it >> 6, d = it & 63;
    const float h = bp1[d] + rel[k][0] * Wp1[d] +
                    rel[k][1] * Wp1[64 + d] + rel[k][2] * Wp1[128 + d];
    h1s[k][d] = fmaxf(h, 0.f);
  }
#pragma unroll
  for (int k = 0; k < 16; k++) {    // gather projected K/V rows (coalesced)
    const size_t row = ((size_t)b * NPTS + nidx[k]) * DOUT;
    kfs[k][tid] = b2f(Kf[row + tid]);
    vfs[k][tid] = b2f(Vf[row + tid]);
  }
  __syncthreads();
#pragma unroll
  for (int i = 0; i < 4; i++) {     // pos = h1 @ Wp2 + bp2
    const int it = tid + i * 256;
    const int k = it >> 6, d = it & 63;
    float acc = bp2[d];
    for (int j2 = 0; j2 < 64; j2++) acc += h1s[k][j2] * Wp2[j2 * 64 + d];
    pos[k][d] = acc;
  }
  __syncthreads();
  if (tid < 64) {                   // logits
    const int k = tid >> 2, h = tid & 3;
    float acc = 0.f;
    for (int d = 0; d < 64; d++)
      acc += qv[h * 64 + d] * (kfs[k][h * 64 + d] + pos[k][d]);
    lg[h][k] = acc * 0.125f;
  }
  __syncthreads();
  if (tid < 4) {                    // softmax over K per head
    const int h = tid;
    float m = -INFINITY;
#pragma unroll
    for (int k = 0; k < 16; k++) m = fmaxf(m, lg[h][k]);
    float e[16], sum = 0.f;
#pragma unroll
    for (int k = 0; k < 16; k++) { e[k] = expf(lg[h][k] - m); sum += e[k]; }
    const float inv = 1.f / sum;
#pragma unroll
    for (int k = 0; k < 16; k++) {
      const float a = e[k] * inv;
      aw[h][k] = a;
      AOUT[(((size_t)b * 4 + h) * NPTS + n) * KNN + k] = a;
    }
  }
  __syncthreads();
  {                                 // out = sum_k attn * (v + pos) -> overwrite Q row
    const int h = tid >> 6, d = tid & 63;
    float acc = 0.f;
#pragma unroll
    for (int k = 0; k < 16; k++) acc += aw[h][k] * (vfs[k][h * 64 + d] + pos[k][d]);
    QOA[(size_t)p * DOUT + tid] = f2b(acc);
  }
}

// ---------------------------------------------------------------------------
// FFN + LN2 + residual: per 8 rows: fc1=relu(x@Wf1+bf1), fc2=fc1@Wf2+bf2,
// out = LN2(fc2)*g2+b2 + skip. skip lives in d_out (f32; read, then
// overwritten by the same thread/element with the final f32 value).
// ---------------------------------------------------------------------------
__global__ __launch_bounds__(256) void ffn_kernel(
    const bf16* __restrict__ OA,
    const float* __restrict__ Wf1, const float* __restrict__ bf1,
    const float* __restrict__ Wf2, const float* __restrict__ bf2,
    const float* __restrict__ g2, const float* __restrict__ b2p,
    float* __restrict__ out) {
  __shared__ float x[8][DOUT];
  __shared__ float y[8][DOUT];
  __shared__ float mu8[8], rs8[8];
  const int tid = threadIdx.x;
  const size_t r0 = (size_t)blockIdx.x * 8;
  const bf16* src = OA + r0 * DOUT;
#pragma unroll
  for (int i = 0; i < 8; i++) x[i][tid] = b2f(src[i * DOUT + tid]);
  __syncthreads();
  float acc[8] = {};
  for (int d = 0; d < DOUT; d += 4) {
    const float w0 = Wf1[(d + 0) * DOUT + tid];
    const float w1 = Wf1[(d + 1) * DOUT + tid];
    const float w2 = Wf1[(d + 2) * DOUT + tid];
    const float w3 = Wf1[(d + 3) * DOUT + tid];
#pragma unroll
    for (int rr = 0; rr < 8; rr++) {
      const float4 v = *(const float4*)&x[rr][d];
      acc[rr] += v.x * w0 + v.y * w1 + v.z * w2 + v.w * w3;
    }
  }
  const float b1v = bf1[tid];
#pragma unroll
  for (int rr = 0; rr < 8; rr++) y[rr][tid] = fmaxf(acc[rr] + b1v, 0.f);
  __syncthreads();
  float acc2[8] = {};
  for (int d = 0; d < DOUT; d += 4) {
    const float w0 = Wf2[(d + 0) * DOUT + tid];
    const float w1 = Wf2[(d + 1) * DOUT + tid];
    const float w2 = Wf2[(d + 2) * DOUT + tid];
    const float w3 = Wf2[(d + 3) * DOUT + tid];
#pragma unroll
    for (int rr = 0; rr < 8; rr++) {
      const float4 v = *(const float4*)&y[rr][d];
      acc2[rr] += v.x * w0 + v.y * w1 + v.z * w2 + v.w * w3;
    }
  }
  const float b2v = bf2[tid];
#pragma unroll
  for (int rr = 0; rr < 8; rr++) x[rr][tid] = acc2[rr] + b2v;   // fc2 -> x
  __syncthreads();
  const int r = tid >> 5, j = tid & 31;
  float s = 0.f;
#pragma unroll
  for (int k2 = 0; k2 < 8; k2++) s += x[r][j + 32 * k2];
  s = rsum32(s);
  if (!j) mu8[r] = s * (1.f / 256.f);
  __syncthreads();
  const float mu = mu8[r];
  float ss = 0.f;
#pragma unroll
  for (int k2 = 0; k2 < 8; k2++) { const float dd = x[r][j + 32 * k2] - mu; ss += dd * dd; }
  ss = rsum32(ss);
  if (!j) rs8[r] = rsqrtf(ss * (1.f / 256.f) + 1e-5f);
  __syncthreads();
  const float gv = g2[tid], bbv = b2p[tid];
#pragma unroll
  for (int rr = 0; rr < 8; rr++) {
    const size_t o = (r0 + rr) * DOUT + tid;
    const float sk = out[o];        // skip stored here by proj_kernel (f32)
    out[o] = (x[rr][tid] - mu8[rr]) * rs8[rr] * gv + bbv + sk;
  }
}

extern "C" void kernel_launch(void* const* d_in, const int* in_sizes, int n_in,
                              void* d_out, int out_size, void* d_ws, size_t ws_size,
                              hipStream_t stream) {
  const float* xyz  = (const float*)d_in[0];
  const float* feat = (const float*)d_in[1];
  const float* Wq   = (const float*)d_in[2];
  const float* bq   = (const float*)d_in[3];
  const float* Wk   = (const float*)d_in[4];
  const float* bk   = (const float*)d_in[5];
  const float* Wv   = (const float*)d_in[6];
  const float* bv   = (const float*)d_in[7];
  const float* Wp1  = (const float*)d_in[8];
  const float* bp1  = (const float*)d_in[9];
  const float* Wp2  = (const float*)d_in[10];
  const float* bp2  = (const float*)d_in[11];
  const float* Wf1  = (const float*)d_in[12];
  const float* bf1  = (const float*)d_in[13];
  const float* Wf2  = (const float*)d_in[14];
  const float* bf2  = (const float*)d_in[15];
  const float* g1   = (const float*)d_in[16];
  const float* b1   = (const float*)d_in[17];
  const float* g2   = (const float*)d_in[18];
  const float* b2   = (const float*)d_in[19];

  float* out  = (float*)d_out;
  float* aout = out + (size_t)TOTPTS * DOUT;  // attn-weights output region (f32)

  // workspace layout (49 MB peak):
  //   [0, 1 MB)    final knn indices, uint16 (persists through attn)
  //   [1, 17 MB)   QOA bf16 (proj -> attn, aliased Q/out-rows)
  //   [17, 33 MB)  Kf bf16
  //   [26, 26.5)   phase: packed xyzw float4 (dead before proj writes Kf)
  //   [33, 49 MB)  Vf bf16
  unsigned short* knn  = (unsigned short*)d_ws;
  float4*         xyzw = (float4*)((char*)d_ws + (size_t)(26 << 20));
  bf16* QOA = (bf16*)((char*)d_ws + (size_t)(1 << 20));
  bf16* Kf  = QOA + (size_t)TOTPTS * DOUT;
  bf16* Vf  = Kf  + (size_t)TOTPTS * DOUT;

  pack_kernel<<<TOTPTS / 256, 256, 0, stream>>>(xyz, xyzw);
  knn_wave_kernel<<<TOTPTS / 4, 256, 0, stream>>>(xyzw, knn);
  proj_kernel<<<TOTPTS / 8, 256, 0, stream>>>(feat, Wq, bq, Wk, bk, Wv, bv, g1, b1,
                                              QOA, Kf, Vf, /*skip->*/out);
  attn_kernel<<<TOTPTS, 256, 0, stream>>>(xyz, knn, QOA, Kf, Vf, Wp1, bp1, Wp2, bp2,
                                          aout);
  ffn_kernel<<<TOTPTS / 8, 256, 0, stream>>>(QOA, Wf1, bf1, Wf2, bf2, g2, b2, out);
}

// Round 9
// 1550.565 us; speedup vs baseline: 4.4707x; 1.4086x over previous
//
#include <hip/hip_runtime.h>
#include <hip/hip_bf16.h>
#include <math.h>

typedef __hip_bfloat16 bf16;

#define NBATCH 4
#define NPTS   8192
#define TOTPTS 32768
#define DIM    128
#define DOUT   256
#define KNN    16

__device__ __forceinline__ float b2f(bf16 x) { return __bfloat162float(x); }
__device__ __forceinline__ bf16 f2b(float x) { return __float2bfloat16(x); }

__device__ __forceinline__ float rsum32(float v) {
#pragma unroll
  for (int o = 16; o; o >>= 1) v += __shfl_down(v, o, 32);
  return v;
}

// ---------------------------------------------------------------------------
// Pack xyz -> (x, y, z, |p|^2) float4 (one coalesced 16B load per candidate).
// ---------------------------------------------------------------------------
__global__ __launch_bounds__(256) void pack_kernel(const float* __restrict__ xyz,
                                                   float4* __restrict__ xyzw) {
  const int p = blockIdx.x * 256 + threadIdx.x;
  const float x = xyz[3 * p], y = xyz[3 * p + 1], z = xyz[3 * p + 2];
  xyzw[p] = make_float4(x, y, z, x * x + y * y + z * z);
}

// ---------------------------------------------------------------------------
// KNN: one wave per query, lane = candidate; ballot makes the rare insert
// wave-uniform (~116 inserts/query, all lanes active on replicated top-16).
// Ascending index order + bd[i] <= dl keep-condition preserves stable
// jax.lax.top_k tie semantics. (Round-8 win: 3030 -> ~off-profile.)
// ---------------------------------------------------------------------------
__global__ __launch_bounds__(256) void knn_wave_kernel(
    const float4* __restrict__ xyzw, unsigned short* __restrict__ knn_out) {
  const int wid  = threadIdx.x >> 6;
  const int lane = threadIdx.x & 63;
  const int q = blockIdx.x * 4 + wid;     // wave-uniform query id
  const int b = q >> 13;
  const float4 me = xyzw[q];
  const float qx = me.x, qy = me.y, qz = me.z, qs = me.w;
  const float4* cb = xyzw + (size_t)b * NPTS;
  float bd[KNN];
  int   bi[KNN];
#pragma unroll
  for (int i = 0; i < KNN; i++) { bd[i] = INFINITY; bi[i] = 0x7fff; }
  for (int g = 0; g < NPTS; g += 64) {
    const float4 t = cb[g + lane];
    const float d2 = qs + t.w - 2.f * (qx * t.x + qy * t.y + qz * t.z);
    unsigned long long mask = __ballot(d2 < bd[KNN - 1]);
    while (mask) {                        // wave-uniform loop
      const int l = __builtin_ctzll(mask);
      mask &= mask - 1;
      const float dl = __int_as_float(
          __builtin_amdgcn_readlane(__float_as_int(d2), l));
      if (dl < bd[KNN - 1]) {
        const int il = g + l;
        float nd[KNN]; int ni[KNN];
#pragma unroll
        for (int i = 0; i < KNN; i++) {   // positional insert, no serial chain
          const bool keep = bd[i] <= dl;  // ties: earlier index stays left
          const bool fromPrev = (i > 0) && (bd[i - 1] > dl);
          nd[i] = keep ? bd[i] : (fromPrev ? bd[i - 1] : dl);
          ni[i] = keep ? bi[i] : (fromPrev ? bi[i - 1] : il);
        }
#pragma unroll
        for (int i = 0; i < KNN; i++) { bd[i] = nd[i]; bi[i] = ni[i]; }
      }
    }
  }
  if (lane == 0) {
#pragma unroll
    for (int i = 0; i < KNN; i++)
      knn_out[(size_t)q * KNN + i] = (unsigned short)bi[i];
  }
}

// ---------------------------------------------------------------------------
// Projections: per 8 rows compute LN1(features), then Q=f@Wq+bq, Kf=f@Wk+bk,
// Vf=f@Wv+bv (bf16 -> ws) and skip=LN1@Wq+bq (f32 -> d_out out-region).
// ---------------------------------------------------------------------------
__global__ __launch_bounds__(256) void proj_kernel(
    const float* __restrict__ feat,
    const float* __restrict__ Wq, const float* __restrict__ bq,
    const float* __restrict__ Wk, const float* __restrict__ bk,
    const float* __restrict__ Wv, const float* __restrict__ bv,
    const float* __restrict__ g1, const float* __restrict__ b1,
    bf16* __restrict__ Q, bf16* __restrict__ Kf, bf16* __restrict__ Vf,
    float* __restrict__ skip) {
  __shared__ float f[8][DIM];
  __shared__ float ln[8][DIM];
  __shared__ float mu8[8], rs8[8];
  const int tid = threadIdx.x;
  const size_t r0 = (size_t)blockIdx.x * 8;
  const float* src = feat + r0 * DIM;
#pragma unroll
  for (int i = 0; i < 4; i++) {
    const int idx = tid + i * 256;
    f[idx >> 7][idx & 127] = src[idx];
  }
  __syncthreads();
  const int r = tid >> 5, j = tid & 31;
  const float a0 = f[r][j], a1 = f[r][j + 32], a2 = f[r][j + 64], a3 = f[r][j + 96];
  float s = rsum32(a0 + a1 + a2 + a3);
  if (!j) mu8[r] = s * (1.f / 128.f);
  __syncthreads();
  const float mu = mu8[r];
  const float d0 = a0 - mu, d1 = a1 - mu, d2 = a2 - mu, d3 = a3 - mu;
  float ss = rsum32(d0 * d0 + d1 * d1 + d2 * d2 + d3 * d3);
  if (!j) rs8[r] = rsqrtf(ss * (1.f / 128.f) + 1e-5f);
  __syncthreads();
  const float rsd = rs8[r];
  ln[r][j]      = d0 * rsd * g1[j]      + b1[j];
  ln[r][j + 32] = d1 * rsd * g1[j + 32] + b1[j + 32];
  ln[r][j + 64] = d2 * rsd * g1[j + 64] + b1[j + 64];
  ln[r][j + 96] = d3 * rsd * g1[j + 96] + b1[j + 96];
  __syncthreads();
  float qa[8] = {}, ka[8] = {}, va[8] = {}, sa[8] = {};
  for (int d = 0; d < DIM; d += 4) {
    const float wq0 = Wq[(d + 0) * DOUT + tid], wq1 = Wq[(d + 1) * DOUT + tid];
    const float wq2 = Wq[(d + 2) * DOUT + tid], wq3 = Wq[(d + 3) * DOUT + tid];
    const float wk0 = Wk[(d + 0) * DOUT + tid], wk1 = Wk[(d + 1) * DOUT + tid];
    const float wk2 = Wk[(d + 2) * DOUT + tid], wk3 = Wk[(d + 3) * DOUT + tid];
    const float wv0 = Wv[(d + 0) * DOUT + tid], wv1 = Wv[(d + 1) * DOUT + tid];
    const float wv2 = Wv[(d + 2) * DOUT + tid], wv3 = Wv[(d + 3) * DOUT + tid];
#pragma unroll
    for (int rr = 0; rr < 8; rr++) {
      const float4 fv = *(const float4*)&f[rr][d];
      const float4 lv = *(const float4*)&ln[rr][d];
      qa[rr] += fv.x * wq0 + fv.y * wq1 + fv.z * wq2 + fv.w * wq3;
      ka[rr] += fv.x * wk0 + fv.y * wk1 + fv.z * wk2 + fv.w * wk3;
      va[rr] += fv.x * wv0 + fv.y * wv1 + fv.z * wv2 + fv.w * wv3;
      sa[rr] += lv.x * wq0 + lv.y * wq1 + lv.z * wq2 + lv.w * wq3;
    }
  }
  const float bqv = bq[tid], bkv = bk[tid], bvv = bv[tid];
#pragma unroll
  for (int rr = 0; rr < 8; rr++) {
    const size_t o = (r0 + rr) * DOUT + tid;
    Q[o]    = f2b(qa[rr] + bqv);
    Kf[o]   = f2b(ka[rr] + bkv);
    Vf[o]   = f2b(va[rr] + bvv);
    skip[o] = sa[rr] + bqv;
  }
}

// ---------------------------------------------------------------------------
// Attention v2: one block per point, wave = head, lane = dim. K/V gathered
// straight into REGISTERS (thread tid only ever needs element tid of each
// row — r8 insight), logits via per-lane partials + 16-accumulator
// __shfl_xor butterfly (every lane ends with all 16 logits -> softmax is
// lane-redundant, barrier-free), pos-MLP via shuffle-broadcast of h1 with
// one shared Wp2 load per j (no 512-LDS-read chains, no kfs/vfs LDS, no
// bank conflicts). 3 barriers total; LDS ~4.5 KB (was 43 KB).
// ---------------------------------------------------------------------------
__global__ __launch_bounds__(256) void attn_kernel(
    const float* __restrict__ xyz, const unsigned short* __restrict__ knn_in,
    bf16* __restrict__ QOA, const bf16* __restrict__ Kf, const bf16* __restrict__ Vf,
    const float* __restrict__ Wp1, const float* __restrict__ bp1,
    const float* __restrict__ Wp2, const float* __restrict__ bp2,
    float* __restrict__ AOUT) {
  __shared__ int   nidxS[16];
  __shared__ float relS[16][3];
  __shared__ float posS[16][65];
  const int tid  = threadIdx.x;
  const int w    = tid >> 6;        // wave id = head
  const int lane = tid & 63;        // lane = dim within head
  const int p = blockIdx.x;
  const int b = p >> 13, n = p & (NPTS - 1);

  if (tid < 16) nidxS[tid] = knn_in[(size_t)p * KNN + tid];
  const float qreg = b2f(QOA[(size_t)p * DOUT + tid]);   // own row, pre-write
  __syncthreads();                  // nidxS ready

  // K/V gather into registers (issued early; waitcnt lands before logits)
  float kreg[16], vreg[16];
  const size_t rowbase = (size_t)b * NPTS;
#pragma unroll
  for (int k = 0; k < 16; k++) {
    const size_t row = (rowbase + (size_t)nidxS[k]) * DOUT + tid;
    kreg[k] = b2f(Kf[row]);
    vreg[k] = b2f(Vf[row]);
  }
  // relative positions (wave 0 only -> barrier below)
  if (tid < 48) {
    const int k = tid / 3, c = tid - 3 * k;
    const float* xb = xyz + (size_t)b * NPTS * 3;
    relS[k][c] = xb[3 * nidxS[k] + c] - xb[3 * n + c];
  }
  __syncthreads();                  // relS ready

  // h1 = relu(rel @ Wp1 + bp1): wave w owns k = 4w+kk, lane holds dim
  const float w0 = Wp1[lane], w1 = Wp1[64 + lane], w2 = Wp1[128 + lane];
  const float bb1 = bp1[lane], bb2 = bp2[lane];
  float h1v[4];
#pragma unroll
  for (int kk = 0; kk < 4; kk++) {
    const int k = w * 4 + kk;
    h1v[kk] = fmaxf(bb1 + relS[k][0] * w0 + relS[k][1] * w1 + relS[k][2] * w2, 0.f);
  }
  // pos = h1 @ Wp2 + bp2 via shuffle-broadcast; one Wp2 load shared by 4 k's
  float acc[4] = {bb2, bb2, bb2, bb2};
#pragma unroll 8
  for (int j2 = 0; j2 < 64; j2++) {
    const float w2v = Wp2[j2 * 64 + lane];
#pragma unroll
    for (int kk = 0; kk < 4; kk++)
      acc[kk] += __shfl(h1v[kk], j2, 64) * w2v;
  }
#pragma unroll
  for (int kk = 0; kk < 4; kk++) posS[w * 4 + kk][lane] = acc[kk];
  __syncthreads();                  // posS ready

  // logits: per-lane partials, butterfly reduce -> all lanes hold all 16
  float posr[16], lg[16];
#pragma unroll
  for (int k = 0; k < 16; k++) {
    posr[k] = posS[k][lane];
    lg[k] = qreg * (kreg[k] + posr[k]);
  }
#pragma unroll
  for (int o = 32; o; o >>= 1) {
#pragma unroll
    for (int k = 0; k < 16; k++) lg[k] += __shfl_xor(lg[k], o, 64);
  }
  // softmax over k (lane-redundant, no sync)
  float m = -INFINITY;
#pragma unroll
  for (int k = 0; k < 16; k++) { lg[k] *= 0.125f; m = fmaxf(m, lg[k]); }
  float sum = 0.f;
#pragma unroll
  for (int k = 0; k < 16; k++) { lg[k] = expf(lg[k] - m); sum += lg[k]; }
  const float inv = 1.f / sum;
#pragma unroll
  for (int k = 0; k < 16; k++) lg[k] *= inv;
  // attn-weight store: lane l<16 writes a[l] (coalesced 64B per wave)
  float av = 0.f;
#pragma unroll
  for (int k = 0; k < 16; k++) if (lane == k) av = lg[k];
  if (lane < 16)
    AOUT[(((size_t)b * 4 + w) * NPTS + n) * KNN + lane] = av;
  // output: sum_k a[k] * (v[k] + pos[k][d]) -> overwrite own Q row
  float o = 0.f;
#pragma unroll
  for (int k = 0; k < 16; k++) o += lg[k] * (vreg[k] + posr[k]);
  QOA[(size_t)p * DOUT + tid] = f2b(o);
}

// ---------------------------------------------------------------------------
// FFN + LN2 + residual: per 8 rows: fc1=relu(x@Wf1+bf1), fc2=fc1@Wf2+bf2,
// out = LN2(fc2)*g2+b2 + skip. skip lives in d_out (f32; read, then
// overwritten by the same thread/element with the final f32 value).
// ---------------------------------------------------------------------------
__global__ __launch_bounds__(256) void ffn_kernel(
    const bf16* __restrict__ OA,
    const float* __restrict__ Wf1, const float* __restrict__ bf1,
    const float* __restrict__ Wf2, const float* __restrict__ bf2,
    const float* __restrict__ g2, const float* __restrict__ b2p,
    float* __restrict__ out) {
  __shared__ float x[8][DOUT];
  __shared__ float y[8][DOUT];
  __shared__ float mu8[8], rs8[8];
  const int tid = threadIdx.x;
  const size_t r0 = (size_t)blockIdx.x * 8;
  const bf16* src = OA + r0 * DOUT;
#pragma unroll
  for (int i = 0; i < 8; i++) x[i][tid] = b2f(src[i * DOUT + tid]);
  __syncthreads();
  float acc[8] = {};
  for (int d = 0; d < DOUT; d += 4) {
    const float w0 = Wf1[(d + 0) * DOUT + tid];
    const float w1 = Wf1[(d + 1) * DOUT + tid];
    const float w2 = Wf1[(d + 2) * DOUT + tid];
    const float w3 = Wf1[(d + 3) * DOUT + tid];
#pragma unroll
    for (int rr = 0; rr < 8; rr++) {
      const float4 v = *(const float4*)&x[rr][d];
      acc[rr] += v.x * w0 + v.y * w1 + v.z * w2 + v.w * w3;
    }
  }
  const float b1v = bf1[tid];
#pragma unroll
  for (int rr = 0; rr < 8; rr++) y[rr][tid] = fmaxf(acc[rr] + b1v, 0.f);
  __syncthreads();
  float acc2[8] = {};
  for (int d = 0; d < DOUT; d += 4) {
    const float w0 = Wf2[(d + 0) * DOUT + tid];
    const float w1 = Wf2[(d + 1) * DOUT + tid];
    const float w2 = Wf2[(d + 2) * DOUT + tid];
    const float w3 = Wf2[(d + 3) * DOUT + tid];
#pragma unroll
    for (int rr = 0; rr < 8; rr++) {
      const float4 v = *(const float4*)&y[rr][d];
      acc2[rr] += v.x * w0 + v.y * w1 + v.z * w2 + v.w * w3;
    }
  }
  const float b2v = bf2[tid];
#pragma unroll
  for (int rr = 0; rr < 8; rr++) x[rr][tid] = acc2[rr] + b2v;   // fc2 -> x
  __syncthreads();
  const int r = tid >> 5, j = tid & 31;
  float s = 0.f;
#pragma unroll
  for (int k2 = 0; k2 < 8; k2++) s += x[r][j + 32 * k2];
  s = rsum32(s);
  if (!j) mu8[r] = s * (1.f / 256.f);
  __syncthreads();
  const float mu = mu8[r];
  float ss = 0.f;
#pragma unroll
  for (int k2 = 0; k2 < 8; k2++) { const float dd = x[r][j + 32 * k2] - mu; ss += dd * dd; }
  ss = rsum32(ss);
  if (!j) rs8[r] = rsqrtf(ss * (1.f / 256.f) + 1e-5f);
  __syncthreads();
  const float gv = g2[tid], bbv = b2p[tid];
#pragma unroll
  for (int rr = 0; rr < 8; rr++) {
    const size_t o = (r0 + rr) * DOUT + tid;
    const float sk = out[o];        // skip stored here by proj_kernel (f32)
    out[o] = (x[rr][tid] - mu8[rr]) * rs8[rr] * gv + bbv + sk;
  }
}

extern "C" void kernel_launch(void* const* d_in, const int* in_sizes, int n_in,
                              void* d_out, int out_size, void* d_ws, size_t ws_size,
                              hipStream_t stream) {
  const float* xyz  = (const float*)d_in[0];
  const float* feat = (const float*)d_in[1];
  const float* Wq   = (const float*)d_in[2];
  const float* bq   = (const float*)d_in[3];
  const float* Wk   = (const float*)d_in[4];
  const float* bk   = (const float*)d_in[5];
  const float* Wv   = (const float*)d_in[6];
  const float* bv   = (const float*)d_in[7];
  const float* Wp1  = (const float*)d_in[8];
  const float* bp1  = (const float*)d_in[9];
  const float* Wp2  = (const float*)d_in[10];
  const float* bp2  = (const float*)d_in[11];
  const float* Wf1  = (const float*)d_in[12];
  const float* bf1  = (const float*)d_in[13];
  const float* Wf2  = (const float*)d_in[14];
  const float* bf2  = (const float*)d_in[15];
  const float* g1   = (const float*)d_in[16];
  const float* b1   = (const float*)d_in[17];
  const float* g2   = (const float*)d_in[18];
  const float* b2   = (const float*)d_in[19];

  float* out  = (float*)d_out;
  float* aout = out + (size_t)TOTPTS * DOUT;  // attn-weights output region (f32)

  // workspace layout (49 MB peak):
  //   [0, 1 MB)    final knn indices, uint16 (persists through attn)
  //   [1, 17 MB)   QOA bf16 (proj -> attn, aliased Q/out-rows)
  //   [17, 33 MB)  Kf bf16
  //   [26, 26.5)   phase: packed xyzw float4 (dead before proj writes Kf)
  //   [33, 49 MB)  Vf bf16
  unsigned short* knn  = (unsigned short*)d_ws;
  float4*         xyzw = (float4*)((char*)d_ws + (size_t)(26 << 20));
  bf16* QOA = (bf16*)((char*)d_ws + (size_t)(1 << 20));
  bf16* Kf  = QOA + (size_t)TOTPTS * DOUT;
  bf16* Vf  = Kf  + (size_t)TOTPTS * DOUT;

  pack_kernel<<<TOTPTS / 256, 256, 0, stream>>>(xyz, xyzw);
  knn_wave_kernel<<<TOTPTS / 4, 256, 0, stream>>>(xyzw, knn);
  proj_kernel<<<TOTPTS / 8, 256, 0, stream>>>(feat, Wq, bq, Wk, bk, Wv, bv, g1, b1,
                                              QOA, Kf, Vf, /*skip->*/out);
  attn_kernel<<<TOTPTS, 256, 0, stream>>>(xyz, knn, QOA, Kf, Vf, Wp1, bp1, Wp2, bp2,
                                          aout);
  ffn_kernel<<<TOTPTS / 8, 256, 0, stream>>>(QOA, Wf1, bf1, Wf2, bf2, g2, b2, out);
}